// Round 1
// baseline (1227.723 us; speedup 1.0000x reference)
//
#include <hip/hip_runtime.h>

#define B 8
#define S 4096
#define H 16
#define DK 128
#define D 2048
#define SCALE 0.08838834764831845f  // 1/sqrt(128)

// ---------------------------------------------------------------- K0: inits
__global__ __launch_bounds__(256) void k0_init(float* __restrict__ qq, float* __restrict__ U,
                                               float* __restrict__ x, float* __restrict__ out,
                                               const float* __restrict__ q_bias,
                                               const float* __restrict__ bv,
                                               const float* __restrict__ bo) {
    int idx = blockIdx.x * 256 + threadIdx.x;
    if (idx < B * D) {
        int d = idx & (D - 1);
        qq[idx]  = q_bias[d];
        x[idx]   = bv[d];
        out[idx] = bo[d];
    }
    if (idx < B * H * D) U[idx] = 0.f;
}

// ---------------------------------------------- K1: qq += query @ Wq (atomic)
// grid (8 dout-chunks x 32 e-chunks), block 256
__global__ __launch_bounds__(256) void k1_qproj(const float* __restrict__ query,
                                                const float* __restrict__ Wq,
                                                float* __restrict__ qq) {
    int dout = blockIdx.x * 256 + threadIdx.x;
    int e0 = blockIdx.y * 64;
    float acc[B] = {};
    #pragma unroll 4
    for (int e = e0; e < e0 + 64; ++e) {
        float w = Wq[(size_t)e * D + dout];
        #pragma unroll
        for (int b = 0; b < B; ++b) acc[b] = fmaf(query[b * D + e], w, acc[b]);
    }
    #pragma unroll
    for (int b = 0; b < B; ++b) atomicAdd(&qq[b * D + dout], acc[b]);
}

// ------------------- K2: A[b][h][e] = sum_d Wk[e, h*128+d] * qq[b, h*128+d]
// grid (16 h x 8 e-chunks of 256), block 256 (thread = e)
__global__ __launch_bounds__(256) void k2_A(const float* __restrict__ Wk,
                                            const float* __restrict__ qq,
                                            float* __restrict__ A) {
    int h = blockIdx.x;
    int e = blockIdx.y * 256 + threadIdx.x;
    const float* wrow = Wk + (size_t)e * D + h * DK;
    const float* qb = qq + h * DK;
    float acc[B] = {};
    #pragma unroll 4
    for (int t = 0; t < DK / 4; ++t) {
        float4 w = *(const float4*)(wrow + 4 * t);
        #pragma unroll
        for (int b = 0; b < B; ++b) {
            const float* q4 = qb + b * D + 4 * t;
            acc[b] += w.x * q4[0] + w.y * q4[1] + w.z * q4[2] + w.w * q4[3];
        }
    }
    #pragma unroll
    for (int b = 0; b < B; ++b) A[((size_t)b * H + h) * D + e] = acc[b];
}

// ---------------- Kq: scores[b][h][j] = qq[b,h,:] . key_pos[j,h,:] (unscaled)
// grid 256 (j/16), block 256 = 16 h (major) x 16 jsub
__global__ __launch_bounds__(256) void kq_pos(const float* __restrict__ key_pos,
                                              const float* __restrict__ qq,
                                              float* __restrict__ scores) {
    int tid = threadIdx.x;
    int h = tid >> 4, jsub = tid & 15;
    int j = blockIdx.x * 16 + jsub;
    const float* kprow = key_pos + ((size_t)j * H + h) * DK;
    float acc[B] = {};
    #pragma unroll 2
    for (int t = 0; t < DK / 4; ++t) {
        float4 kp4 = *(const float4*)(kprow + 4 * t);
        #pragma unroll
        for (int b = 0; b < B; ++b) {
            const float* q4 = qq + b * D + h * DK + 4 * t;
            acc[b] += kp4.x * q4[0] + kp4.y * q4[1] + kp4.z * q4[2] + kp4.w * q4[3];
        }
    }
    #pragma unroll
    for (int b = 0; b < B; ++b) scores[((size_t)b * H + h) * S + j] = acc[b];
}

// --------------- K3: scores[b][h][j] += key[j,b,:] . A[b,h,:]  (the big one)
// grid (64 j-tiles, 8 b, 4 e-quarters), block 256 = 64 j x 4 h-groups
__global__ __launch_bounds__(256) void k3_scores(const float* __restrict__ key,
                                                 const float* __restrict__ A,
                                                 float* __restrict__ scores) {
    int tid = threadIdx.x;
    int j  = blockIdx.x * 64 + (tid >> 2);
    int b  = blockIdx.y;
    int hq = tid & 3;
    int eq = blockIdx.z;
    const float* krow = key + ((size_t)j * B + b) * D + eq * 512;
    const float* A0 = A + ((size_t)b * H + hq * 4) * D + eq * 512;
    float a0 = 0.f, a1 = 0.f, a2 = 0.f, a3 = 0.f;
    #pragma unroll 4
    for (int t = 0; t < 128; ++t) {
        float4 k4 = *(const float4*)(krow + 4 * t);
        float4 x0 = *(const float4*)(A0 + 0 * D + 4 * t);
        float4 x1 = *(const float4*)(A0 + 1 * D + 4 * t);
        float4 x2 = *(const float4*)(A0 + 2 * D + 4 * t);
        float4 x3 = *(const float4*)(A0 + 3 * D + 4 * t);
        a0 += k4.x * x0.x + k4.y * x0.y + k4.z * x0.z + k4.w * x0.w;
        a1 += k4.x * x1.x + k4.y * x1.y + k4.z * x1.z + k4.w * x1.w;
        a2 += k4.x * x2.x + k4.y * x2.y + k4.z * x2.z + k4.w * x2.w;
        a3 += k4.x * x3.x + k4.y * x3.y + k4.z * x3.z + k4.w * x3.w;
    }
    float* sp = scores + ((size_t)b * H + hq * 4) * S + j;
    atomicAdd(sp + 0 * S, a0);
    atomicAdd(sp + 1 * S, a1);
    atomicAdd(sp + 2 * S, a2);
    atomicAdd(sp + 3 * S, a3);
}

// --------------------- K4: softmax over j per (b,h); applies SCALE, in-place
__global__ __launch_bounds__(256) void k4_softmax(float* __restrict__ scores) {
    int bh = blockIdx.x;
    float* row = scores + (size_t)bh * S;
    __shared__ float red[4];
    int tid = threadIdx.x, lane = tid & 63, w = tid >> 6;
    float m = -3.0e38f;
    for (int i = tid; i < S; i += 256) m = fmaxf(m, row[i]);
    #pragma unroll
    for (int o = 32; o; o >>= 1) m = fmaxf(m, __shfl_xor(m, o, 64));
    if (lane == 0) red[w] = m;
    __syncthreads();
    float M = fmaxf(fmaxf(red[0], red[1]), fmaxf(red[2], red[3]));
    __syncthreads();
    float s = 0.f;
    for (int i = tid; i < S; i += 256) {
        float e = __expf((row[i] - M) * SCALE);
        row[i] = e;
        s += e;
    }
    #pragma unroll
    for (int o = 32; o; o >>= 1) s += __shfl_xor(s, o, 64);
    if (lane == 0) red[w] = s;
    __syncthreads();
    float inv = 1.f / (red[0] + red[1] + red[2] + red[3]);
    for (int i = tid; i < S; i += 256) row[i] *= inv;
}

// ------------- K5: U[b][h][e] += sum_j attn[b][h][j] * value[j,b,e] (atomic)
// grid (32 j-tiles of 128, 8 b), block 512 (thread = float4 chunk of e)
__global__ __launch_bounds__(512) void k5_U(const float* __restrict__ value,
                                            const float* __restrict__ attn,
                                            float* __restrict__ U) {
    int tid = threadIdx.x;
    int b = blockIdx.y;
    int j0 = blockIdx.x * 128;
    const float* vbase = value + ((size_t)j0 * B + b) * D + tid * 4;
    float4 acc[H];
    #pragma unroll
    for (int h = 0; h < H; ++h) acc[h] = make_float4(0.f, 0.f, 0.f, 0.f);
    for (int jj = 0; jj < 128; jj += 4) {
        float4 v0 = *(const float4*)(vbase + (size_t)(jj + 0) * B * D);
        float4 v1 = *(const float4*)(vbase + (size_t)(jj + 1) * B * D);
        float4 v2 = *(const float4*)(vbase + (size_t)(jj + 2) * B * D);
        float4 v3 = *(const float4*)(vbase + (size_t)(jj + 3) * B * D);
        #pragma unroll
        for (int h = 0; h < H; ++h) {
            float4 wv = *(const float4*)(attn + ((size_t)b * H + h) * S + j0 + jj);
            acc[h].x += wv.x * v0.x + wv.y * v1.x + wv.z * v2.x + wv.w * v3.x;
            acc[h].y += wv.x * v0.y + wv.y * v1.y + wv.z * v2.y + wv.w * v3.y;
            acc[h].z += wv.x * v0.z + wv.y * v1.z + wv.z * v2.z + wv.w * v3.z;
            acc[h].w += wv.x * v0.w + wv.y * v1.w + wv.z * v2.w + wv.w * v3.w;
        }
    }
    float* ub = U + (size_t)b * H * D + tid * 4;
    #pragma unroll
    for (int h = 0; h < H; ++h) {
        atomicAdd(ub + h * D + 0, acc[h].x);
        atomicAdd(ub + h * D + 1, acc[h].y);
        atomicAdd(ub + h * D + 2, acc[h].z);
        atomicAdd(ub + h * D + 3, acc[h].w);
    }
}

// ------------- K6: x[b][h*128+d] += sum_e U[b][h][e] * Wv[e, h*128+d] (atomic)
// grid (64 e-chunks of 32, 16 h), block 128 (thread = d)
__global__ __launch_bounds__(128) void k6_xv(const float* __restrict__ Wv,
                                             const float* __restrict__ U,
                                             float* __restrict__ x) {
    int d = threadIdx.x;
    int h = blockIdx.y;
    int e0 = blockIdx.x * 32;
    float acc[B] = {};
    #pragma unroll 4
    for (int ee = 0; ee < 32; ++ee) {
        int e = e0 + ee;
        float w = Wv[(size_t)e * D + h * DK + d];
        #pragma unroll
        for (int b = 0; b < B; ++b)
            acc[b] = fmaf(U[((size_t)b * H + h) * D + e], w, acc[b]);
    }
    #pragma unroll
    for (int b = 0; b < B; ++b) atomicAdd(&x[b * D + h * DK + d], acc[b]);
}

// ---------------------------------------- K7: out += x @ Wo (atomic, bo in K0)
__global__ __launch_bounds__(256) void k7_out(const float* __restrict__ x,
                                              const float* __restrict__ Wo,
                                              float* __restrict__ out) {
    int dout = blockIdx.x * 256 + threadIdx.x;
    int e0 = blockIdx.y * 64;
    float acc[B] = {};
    #pragma unroll 4
    for (int e = e0; e < e0 + 64; ++e) {
        float w = Wo[(size_t)e * D + dout];
        #pragma unroll
        for (int b = 0; b < B; ++b) acc[b] = fmaf(x[b * D + e], w, acc[b]);
    }
    #pragma unroll
    for (int b = 0; b < B; ++b) atomicAdd(&out[b * D + dout], acc[b]);
}

extern "C" void kernel_launch(void* const* d_in, const int* in_sizes, int n_in,
                              void* d_out, int out_size, void* d_ws, size_t ws_size,
                              hipStream_t stream) {
    const float* query   = (const float*)d_in[0];
    const float* key     = (const float*)d_in[1];
    const float* value   = (const float*)d_in[2];
    const float* Wq      = (const float*)d_in[3];
    const float* Wk      = (const float*)d_in[4];
    const float* Wv      = (const float*)d_in[5];
    const float* bv      = (const float*)d_in[6];
    const float* Wo      = (const float*)d_in[7];
    const float* bo      = (const float*)d_in[8];
    const float* key_pos = (const float*)d_in[9];
    const float* q_bias  = (const float*)d_in[10];
    float* out = (float*)d_out;

    float* ws     = (float*)d_ws;
    float* qq     = ws;                 // B*D        = 16384
    float* A      = ws + 16384;         // B*H*D      = 262144
    float* scores = ws + 278528;        // B*H*S      = 524288 (also attn, in place)
    float* U      = ws + 802816;        // B*H*D      = 262144
    float* x      = ws + 1064960;       // B*D        = 16384

    hipLaunchKernelGGL(k0_init,    dim3(1024),      dim3(256), 0, stream, qq, U, x, out, q_bias, bv, bo);
    hipLaunchKernelGGL(k1_qproj,   dim3(8, 32),     dim3(256), 0, stream, query, Wq, qq);
    hipLaunchKernelGGL(k2_A,       dim3(16, 8),     dim3(256), 0, stream, Wk, qq, A);
    hipLaunchKernelGGL(kq_pos,     dim3(256),       dim3(256), 0, stream, key_pos, qq, scores);
    hipLaunchKernelGGL(k3_scores,  dim3(64, 8, 4),  dim3(256), 0, stream, key, A, scores);
    hipLaunchKernelGGL(k4_softmax, dim3(128),       dim3(256), 0, stream, scores);
    hipLaunchKernelGGL(k5_U,       dim3(32, 8),     dim3(512), 0, stream, value, scores, U);
    hipLaunchKernelGGL(k6_xv,      dim3(64, 16),    dim3(128), 0, stream, Wv, U, x);
    hipLaunchKernelGGL(k7_out,     dim3(8, 32),     dim3(256), 0, stream, x, Wo, out);
}

// Round 2
// 894.270 us; speedup vs baseline: 1.3729x; 1.3729x over previous
//
#include <hip/hip_runtime.h>

#define B 8
#define S 4096
#define H 16
#define DK 128
#define D 2048
#define SCALE 0.08838834764831845f  // 1/sqrt(128)

// ---------------------------------------------------------------- K0: inits
__global__ __launch_bounds__(256) void k0_init(float* __restrict__ qq, float* __restrict__ U,
                                               float* __restrict__ x, float* __restrict__ out,
                                               const float* __restrict__ q_bias,
                                               const float* __restrict__ bv,
                                               const float* __restrict__ bo) {
    int idx = blockIdx.x * 256 + threadIdx.x;
    if (idx < B * D) {
        int d = idx & (D - 1);
        qq[idx]  = q_bias[d];
        x[idx]   = bv[d];
        out[idx] = bo[d];
    }
    if (idx < B * H * D) U[idx] = 0.f;
}

// ---------------------------------------------- K1: qq += query @ Wq (atomic)
__global__ __launch_bounds__(256) void k1_qproj(const float* __restrict__ query,
                                                const float* __restrict__ Wq,
                                                float* __restrict__ qq) {
    int dout = blockIdx.x * 256 + threadIdx.x;
    int e0 = blockIdx.y * 64;
    float acc[B] = {};
    #pragma unroll 4
    for (int e = e0; e < e0 + 64; ++e) {
        float w = Wq[(size_t)e * D + dout];
        #pragma unroll
        for (int b = 0; b < B; ++b) acc[b] = fmaf(query[b * D + e], w, acc[b]);
    }
    #pragma unroll
    for (int b = 0; b < B; ++b) atomicAdd(&qq[b * D + dout], acc[b]);
}

// ------------------- K2: A[b][h][e] = sum_d Wk[e, h*128+d] * qq[b, h*128+d]
__global__ __launch_bounds__(256) void k2_A(const float* __restrict__ Wk,
                                            const float* __restrict__ qq,
                                            float* __restrict__ A) {
    int h = blockIdx.x;
    int e = blockIdx.y * 256 + threadIdx.x;
    const float* wrow = Wk + (size_t)e * D + h * DK;
    const float* qb = qq + h * DK;
    float acc[B] = {};
    #pragma unroll 4
    for (int t = 0; t < DK / 4; ++t) {
        float4 w = *(const float4*)(wrow + 4 * t);
        #pragma unroll
        for (int b = 0; b < B; ++b) {
            const float* q4 = qb + b * D + 4 * t;
            acc[b] += w.x * q4[0] + w.y * q4[1] + w.z * q4[2] + w.w * q4[3];
        }
    }
    #pragma unroll
    for (int b = 0; b < B; ++b) A[((size_t)b * H + h) * D + e] = acc[b];
}

// ---------------- Kq: scores[b][h][j] = qq[b,h,:] . key_pos[j,h,:] (unscaled)
// Wave-cooperative: 64 lanes span the 256 contiguous floats of an h-pair
// slice of one key_pos row (coalesced 1 KB/wave), butterfly-reduce per half.
// grid 512, block 256 (4 waves); each wave does 16 (j,hh) tasks.
__global__ __launch_bounds__(256) void kq_pos(const float* __restrict__ key_pos,
                                              const float* __restrict__ qq,
                                              float* __restrict__ scores) {
    int tid = threadIdx.x;
    int lane = tid & 63;
    int wave = tid >> 6;
    int lane31 = lane & 31;
    int half = lane >> 5;  // h = 2*hh + half
    for (int t = 0; t < 16; ++t) {
        int task = (blockIdx.x * 4 + wave) * 16 + t;   // 0 .. 32767
        int j = task >> 3;
        int hh = task & 7;
        float4 kp4 = *(const float4*)(key_pos + (size_t)j * D + hh * 256 + lane * 4);
        int h = hh * 2 + half;
        #pragma unroll
        for (int b = 0; b < B; ++b) {
            float4 q4 = *(const float4*)(qq + (size_t)b * D + hh * 256 + lane * 4);
            float v = kp4.x * q4.x + kp4.y * q4.y + kp4.z * q4.z + kp4.w * q4.w;
            v += __shfl_xor(v, 1, 64);
            v += __shfl_xor(v, 2, 64);
            v += __shfl_xor(v, 4, 64);
            v += __shfl_xor(v, 8, 64);
            v += __shfl_xor(v, 16, 64);
            if (lane31 == 0) scores[((size_t)b * H + h) * S + j] = v;
        }
    }
}

// --------------- K3: scores[b][h][j] += key[j,b,:] . A[b,h,:]  (the big one)
// LDS-staged: block = (64 j-rows, one b). 16 stages of 128 floats of e:
// coalesced global->LDS staging, then lane=jslot reads its row via
// ds_read_b128 (stride 33 f4 -> bank-uniform), wave=h-group of 4 streams A
// at a wave-uniform (scalar) address. One owner per (b,h,j): plain +=.
#define TJ 64
#define EC 128
#define ECF4 32
#define KST 33  // f4 stride: 32 + 1 pad -> (jslot*33+c)&7 uniform across lanes
__global__ __launch_bounds__(256) void k3_scores(const float* __restrict__ key,
                                                 const float* __restrict__ A,
                                                 float* __restrict__ scores) {
    __shared__ float4 klds[TJ * KST];  // 33792 B -> 4 blocks/CU
    int tid = threadIdx.x;
    int b = blockIdx.y;
    int j0 = blockIdx.x * TJ;
    int jslot = tid & 63;
    int h0 = __builtin_amdgcn_readfirstlane((tid >> 6) << 2);  // 0,4,8,12
    const float* Ab = A + ((size_t)b * H + h0) * D;
    float acc0 = 0.f, acc1 = 0.f, acc2 = 0.f, acc3 = 0.f;

    int srow = tid >> 5;   // 0..7
    int scol = tid & 31;   // f4 within row chunk
    for (int s = 0; s < D / EC; ++s) {
        __syncthreads();  // protect klds from previous stage's readers
        const float* gp = key + ((size_t)(j0 + srow) * B + b) * D + s * EC + scol * 4;
        #pragma unroll
        for (int p = 0; p < 8; ++p) {
            klds[(srow + p * 8) * KST + scol] = *(const float4*)(gp + (size_t)p * 8 * B * D);
        }
        __syncthreads();
        const float* Ac = Ab + s * EC;
        #pragma unroll 8
        for (int c = 0; c < ECF4; ++c) {
            float4 k4 = klds[jslot * KST + c];
            float4 a0 = *(const float4*)(Ac + 0 * D + c * 4);
            float4 a1 = *(const float4*)(Ac + 1 * D + c * 4);
            float4 a2 = *(const float4*)(Ac + 2 * D + c * 4);
            float4 a3 = *(const float4*)(Ac + 3 * D + c * 4);
            acc0 += k4.x * a0.x + k4.y * a0.y + k4.z * a0.z + k4.w * a0.w;
            acc1 += k4.x * a1.x + k4.y * a1.y + k4.z * a1.z + k4.w * a1.w;
            acc2 += k4.x * a2.x + k4.y * a2.y + k4.z * a2.z + k4.w * a2.w;
            acc3 += k4.x * a3.x + k4.y * a3.y + k4.z * a3.z + k4.w * a3.w;
        }
    }
    float* sp = scores + ((size_t)b * H + h0) * S + j0 + jslot;
    sp[0 * S] += acc0;
    sp[1 * S] += acc1;
    sp[2 * S] += acc2;
    sp[3 * S] += acc3;
}

// --------------------- K4: softmax over j per (b,h); applies SCALE, in-place
__global__ __launch_bounds__(256) void k4_softmax(float* __restrict__ scores) {
    int bh = blockIdx.x;
    float* row = scores + (size_t)bh * S;
    __shared__ float red[4];
    int tid = threadIdx.x, lane = tid & 63, w = tid >> 6;
    float m = -3.0e38f;
    for (int i = tid; i < S; i += 256) m = fmaxf(m, row[i]);
    #pragma unroll
    for (int o = 32; o; o >>= 1) m = fmaxf(m, __shfl_xor(m, o, 64));
    if (lane == 0) red[w] = m;
    __syncthreads();
    float M = fmaxf(fmaxf(red[0], red[1]), fmaxf(red[2], red[3]));
    __syncthreads();
    float s = 0.f;
    for (int i = tid; i < S; i += 256) {
        float e = __expf((row[i] - M) * SCALE);
        row[i] = e;
        s += e;
    }
    #pragma unroll
    for (int o = 32; o; o >>= 1) s += __shfl_xor(s, o, 64);
    if (lane == 0) red[w] = s;
    __syncthreads();
    float inv = 1.f / (red[0] + red[1] + red[2] + red[3]);
    for (int i = tid; i < S; i += 256) row[i] *= inv;
}

// ------------- K5: U[b][h][e] += sum_j attn[b][h][j] * value[j,b,e] (atomic)
__global__ __launch_bounds__(512) void k5_U(const float* __restrict__ value,
                                            const float* __restrict__ attn,
                                            float* __restrict__ U) {
    int tid = threadIdx.x;
    int b = blockIdx.y;
    int j0 = blockIdx.x * 128;
    const float* vbase = value + ((size_t)j0 * B + b) * D + tid * 4;
    float4 acc[H];
    #pragma unroll
    for (int h = 0; h < H; ++h) acc[h] = make_float4(0.f, 0.f, 0.f, 0.f);
    for (int jj = 0; jj < 128; jj += 4) {
        float4 v0 = *(const float4*)(vbase + (size_t)(jj + 0) * B * D);
        float4 v1 = *(const float4*)(vbase + (size_t)(jj + 1) * B * D);
        float4 v2 = *(const float4*)(vbase + (size_t)(jj + 2) * B * D);
        float4 v3 = *(const float4*)(vbase + (size_t)(jj + 3) * B * D);
        #pragma unroll
        for (int h = 0; h < H; ++h) {
            float4 wv = *(const float4*)(attn + ((size_t)b * H + h) * S + j0 + jj);
            acc[h].x += wv.x * v0.x + wv.y * v1.x + wv.z * v2.x + wv.w * v3.x;
            acc[h].y += wv.x * v0.y + wv.y * v1.y + wv.z * v2.y + wv.w * v3.y;
            acc[h].z += wv.x * v0.z + wv.y * v1.z + wv.z * v2.z + wv.w * v3.z;
            acc[h].w += wv.x * v0.w + wv.y * v1.w + wv.z * v2.w + wv.w * v3.w;
        }
    }
    float* ub = U + (size_t)b * H * D + tid * 4;
    #pragma unroll
    for (int h = 0; h < H; ++h) {
        atomicAdd(ub + h * D + 0, acc[h].x);
        atomicAdd(ub + h * D + 1, acc[h].y);
        atomicAdd(ub + h * D + 2, acc[h].z);
        atomicAdd(ub + h * D + 3, acc[h].w);
    }
}

// ------------- K6: x[b][h*128+d] += sum_e U[b][h][e] * Wv[e, h*128+d] (atomic)
__global__ __launch_bounds__(128) void k6_xv(const float* __restrict__ Wv,
                                             const float* __restrict__ U,
                                             float* __restrict__ x) {
    int d = threadIdx.x;
    int h = blockIdx.y;
    int e0 = blockIdx.x * 32;
    float acc[B] = {};
    #pragma unroll 4
    for (int ee = 0; ee < 32; ++ee) {
        int e = e0 + ee;
        float w = Wv[(size_t)e * D + h * DK + d];
        #pragma unroll
        for (int b = 0; b < B; ++b)
            acc[b] = fmaf(U[((size_t)b * H + h) * D + e], w, acc[b]);
    }
    #pragma unroll
    for (int b = 0; b < B; ++b) atomicAdd(&x[b * D + h * DK + d], acc[b]);
}

// ---------------------------------------- K7: out += x @ Wo (atomic, bo in K0)
__global__ __launch_bounds__(256) void k7_out(const float* __restrict__ x,
                                              const float* __restrict__ Wo,
                                              float* __restrict__ out) {
    int dout = blockIdx.x * 256 + threadIdx.x;
    int e0 = blockIdx.y * 64;
    float acc[B] = {};
    #pragma unroll 4
    for (int e = e0; e < e0 + 64; ++e) {
        float w = Wo[(size_t)e * D + dout];
        #pragma unroll
        for (int b = 0; b < B; ++b) acc[b] = fmaf(x[b * D + e], w, acc[b]);
    }
    #pragma unroll
    for (int b = 0; b < B; ++b) atomicAdd(&out[b * D + dout], acc[b]);
}

extern "C" void kernel_launch(void* const* d_in, const int* in_sizes, int n_in,
                              void* d_out, int out_size, void* d_ws, size_t ws_size,
                              hipStream_t stream) {
    const float* query   = (const float*)d_in[0];
    const float* key     = (const float*)d_in[1];
    const float* value   = (const float*)d_in[2];
    const float* Wq      = (const float*)d_in[3];
    const float* Wk      = (const float*)d_in[4];
    const float* Wv      = (const float*)d_in[5];
    const float* bv      = (const float*)d_in[6];
    const float* Wo      = (const float*)d_in[7];
    const float* bo      = (const float*)d_in[8];
    const float* key_pos = (const float*)d_in[9];
    const float* q_bias  = (const float*)d_in[10];
    float* out = (float*)d_out;

    float* ws     = (float*)d_ws;
    float* qq     = ws;                 // B*D        = 16384
    float* A      = ws + 16384;         // B*H*D      = 262144
    float* scores = ws + 278528;        // B*H*S      = 524288 (also attn, in place)
    float* U      = ws + 802816;        // B*H*D      = 262144
    float* x      = ws + 1064960;       // B*D        = 16384

    hipLaunchKernelGGL(k0_init,    dim3(1024),      dim3(256), 0, stream, qq, U, x, out, q_bias, bv, bo);
    hipLaunchKernelGGL(k1_qproj,   dim3(8, 32),     dim3(256), 0, stream, query, Wq, qq);
    hipLaunchKernelGGL(k2_A,       dim3(16, 8),     dim3(256), 0, stream, Wk, qq, A);
    hipLaunchKernelGGL(kq_pos,     dim3(512),       dim3(256), 0, stream, key_pos, qq, scores);
    hipLaunchKernelGGL(k3_scores,  dim3(64, 8),     dim3(256), 0, stream, key, A, scores);
    hipLaunchKernelGGL(k4_softmax, dim3(128),       dim3(256), 0, stream, scores);
    hipLaunchKernelGGL(k5_U,       dim3(32, 8),     dim3(512), 0, stream, value, scores, U);
    hipLaunchKernelGGL(k6_xv,      dim3(64, 16),    dim3(128), 0, stream, Wv, U, x);
    hipLaunchKernelGGL(k7_out,     dim3(8, 32),     dim3(256), 0, stream, x, Wo, out);
}

// Round 3
// 789.879 us; speedup vs baseline: 1.5543x; 1.1322x over previous
//
#include <hip/hip_runtime.h>

#define B 8
#define S 4096
#define H 16
#define DK 128
#define D 2048
#define SCALE 0.08838834764831845f  // 1/sqrt(128)

// ---------------------------------------------------------------- K0: inits
__global__ __launch_bounds__(256) void k0_init(float* __restrict__ qq,
                                               float* __restrict__ x, float* __restrict__ out,
                                               const float* __restrict__ q_bias,
                                               const float* __restrict__ bv,
                                               const float* __restrict__ bo) {
    int idx = blockIdx.x * 256 + threadIdx.x;
    if (idx < B * D) {
        int d = idx & (D - 1);
        qq[idx]  = q_bias[d];
        x[idx]   = bv[d];
        out[idx] = bo[d];
    }
}

// ---------------------------------------------- K1: qq += query @ Wq (atomic)
__global__ __launch_bounds__(256) void k1_qproj(const float* __restrict__ query,
                                                const float* __restrict__ Wq,
                                                float* __restrict__ qq) {
    int dout = blockIdx.x * 256 + threadIdx.x;
    int e0 = blockIdx.y * 64;
    float acc[B] = {};
    #pragma unroll 4
    for (int e = e0; e < e0 + 64; ++e) {
        float w = Wq[(size_t)e * D + dout];
        #pragma unroll
        for (int b = 0; b < B; ++b) acc[b] = fmaf(query[b * D + e], w, acc[b]);
    }
    #pragma unroll
    for (int b = 0; b < B; ++b) atomicAdd(&qq[b * D + dout], acc[b]);
}

// ------------------- K2: A[b][h][e] = sum_d Wk[e, h*128+d] * qq[b, h*128+d]
// Wave-cooperative: wave owns one e-row of Wk; 8 coalesced 1 KB f4 sweeps
// cover all 2048 columns; each sweep holds an h-pair (32 lanes per h);
// butterfly-reduce per half. grid 512, block 256 (4 waves = 4 e-rows).
__global__ __launch_bounds__(256) void k2_A(const float* __restrict__ Wk,
                                            const float* __restrict__ qq,
                                            float* __restrict__ A) {
    int tid = threadIdx.x;
    int lane = tid & 63, wave = tid >> 6;
    int lane31 = lane & 31, half = lane >> 5;
    int e = blockIdx.x * 4 + wave;
    const float* wrow = Wk + (size_t)e * D;
    #pragma unroll
    for (int p = 0; p < 8; ++p) {
        float4 w4 = *(const float4*)(wrow + p * 256 + lane * 4);
        int h = p * 2 + half;
        #pragma unroll
        for (int b = 0; b < B; ++b) {
            float4 q4 = *(const float4*)(qq + (size_t)b * D + p * 256 + lane * 4);
            float v = w4.x * q4.x + w4.y * q4.y + w4.z * q4.z + w4.w * q4.w;
            v += __shfl_xor(v, 1, 64);
            v += __shfl_xor(v, 2, 64);
            v += __shfl_xor(v, 4, 64);
            v += __shfl_xor(v, 8, 64);
            v += __shfl_xor(v, 16, 64);
            if (lane31 == 0) A[((size_t)b * H + h) * D + e] = v;
        }
    }
}

// ---------------- Kq: scores[b][h][j] = qq[b,h,:] . key_pos[j,h,:] (unscaled)
__global__ __launch_bounds__(256) void kq_pos(const float* __restrict__ key_pos,
                                              const float* __restrict__ qq,
                                              float* __restrict__ scores) {
    int tid = threadIdx.x;
    int lane = tid & 63;
    int wave = tid >> 6;
    int lane31 = lane & 31;
    int half = lane >> 5;  // h = 2*hh + half
    for (int t = 0; t < 16; ++t) {
        int task = (blockIdx.x * 4 + wave) * 16 + t;   // 0 .. 32767
        int j = task >> 3;
        int hh = task & 7;
        float4 kp4 = *(const float4*)(key_pos + (size_t)j * D + hh * 256 + lane * 4);
        int h = hh * 2 + half;
        #pragma unroll
        for (int b = 0; b < B; ++b) {
            float4 q4 = *(const float4*)(qq + (size_t)b * D + hh * 256 + lane * 4);
            float v = kp4.x * q4.x + kp4.y * q4.y + kp4.z * q4.z + kp4.w * q4.w;
            v += __shfl_xor(v, 1, 64);
            v += __shfl_xor(v, 2, 64);
            v += __shfl_xor(v, 4, 64);
            v += __shfl_xor(v, 8, 64);
            v += __shfl_xor(v, 16, 64);
            if (lane31 == 0) scores[((size_t)b * H + h) * S + j] = v;
        }
    }
}

// --------------- K3: scores[b][h][j] += key[j,b,:] . A[b,h,:]  (the big one)
#define TJ 64
#define EC 128
#define ECF4 32
#define KST 33  // f4 stride: 32 + 1 pad
__global__ __launch_bounds__(256) void k3_scores(const float* __restrict__ key,
                                                 const float* __restrict__ A,
                                                 float* __restrict__ scores) {
    __shared__ float4 klds[TJ * KST];  // 33792 B
    int tid = threadIdx.x;
    int b = blockIdx.y;
    int j0 = blockIdx.x * TJ;
    int jslot = tid & 63;
    int h0 = __builtin_amdgcn_readfirstlane((tid >> 6) << 2);  // 0,4,8,12
    const float* Ab = A + ((size_t)b * H + h0) * D;
    float acc0 = 0.f, acc1 = 0.f, acc2 = 0.f, acc3 = 0.f;

    int srow = tid >> 5;   // 0..7
    int scol = tid & 31;   // f4 within row chunk
    for (int s = 0; s < D / EC; ++s) {
        __syncthreads();
        const float* gp = key + ((size_t)(j0 + srow) * B + b) * D + s * EC + scol * 4;
        #pragma unroll
        for (int p = 0; p < 8; ++p) {
            klds[(srow + p * 8) * KST + scol] = *(const float4*)(gp + (size_t)p * 8 * B * D);
        }
        __syncthreads();
        const float* Ac = Ab + s * EC;
        #pragma unroll 8
        for (int c = 0; c < ECF4; ++c) {
            float4 k4 = klds[jslot * KST + c];
            float4 a0 = *(const float4*)(Ac + 0 * D + c * 4);
            float4 a1 = *(const float4*)(Ac + 1 * D + c * 4);
            float4 a2 = *(const float4*)(Ac + 2 * D + c * 4);
            float4 a3 = *(const float4*)(Ac + 3 * D + c * 4);
            acc0 += k4.x * a0.x + k4.y * a0.y + k4.z * a0.z + k4.w * a0.w;
            acc1 += k4.x * a1.x + k4.y * a1.y + k4.z * a1.z + k4.w * a1.w;
            acc2 += k4.x * a2.x + k4.y * a2.y + k4.z * a2.z + k4.w * a2.w;
            acc3 += k4.x * a3.x + k4.y * a3.y + k4.z * a3.z + k4.w * a3.w;
        }
    }
    float* sp = scores + ((size_t)b * H + h0) * S + j0 + jslot;
    sp[0 * S] += acc0;
    sp[1 * S] += acc1;
    sp[2 * S] += acc2;
    sp[3 * S] += acc3;
}

// --------------------- K4: softmax over j per (b,h); applies SCALE, in-place
__global__ __launch_bounds__(256) void k4_softmax(float* __restrict__ scores) {
    int bh = blockIdx.x;
    float* row = scores + (size_t)bh * S;
    __shared__ float red[4];
    int tid = threadIdx.x, lane = tid & 63, w = tid >> 6;
    float m = -3.0e38f;
    for (int i = tid; i < S; i += 256) m = fmaxf(m, row[i]);
    #pragma unroll
    for (int o = 32; o; o >>= 1) m = fmaxf(m, __shfl_xor(m, o, 64));
    if (lane == 0) red[w] = m;
    __syncthreads();
    float M = fmaxf(fmaxf(red[0], red[1]), fmaxf(red[2], red[3]));
    __syncthreads();
    float s = 0.f;
    for (int i = tid; i < S; i += 256) {
        float e = __expf((row[i] - M) * SCALE);
        row[i] = e;
        s += e;
    }
    #pragma unroll
    for (int o = 32; o; o >>= 1) s += __shfl_xor(s, o, 64);
    if (lane == 0) red[w] = s;
    __syncthreads();
    float inv = 1.f / (red[0] + red[1] + red[2] + red[3]);
    for (int i = tid; i < S; i += 256) row[i] *= inv;
}

// ------- K5: U_part[jt][b][h][e] = sum_{j in tile} attn[b][h][j] * value[j,b,e]
// No atomics: each (jt,b) block owns its partial slice; coalesced f4 stores.
// grid (JT, 8 b), block 512 (thread = f4 chunk of e).
__global__ __launch_bounds__(512) void k5_U(const float* __restrict__ value,
                                            const float* __restrict__ attn,
                                            float* __restrict__ Upart, int jlen) {
    int tid = threadIdx.x;
    int b = blockIdx.y;
    int jt = blockIdx.x;
    int j0 = jt * jlen;
    const float* vbase = value + ((size_t)j0 * B + b) * D + tid * 4;
    float4 acc[H];
    #pragma unroll
    for (int h = 0; h < H; ++h) acc[h] = make_float4(0.f, 0.f, 0.f, 0.f);
    for (int jj = 0; jj < jlen; jj += 4) {
        float4 v0 = *(const float4*)(vbase + (size_t)(jj + 0) * B * D);
        float4 v1 = *(const float4*)(vbase + (size_t)(jj + 1) * B * D);
        float4 v2 = *(const float4*)(vbase + (size_t)(jj + 2) * B * D);
        float4 v3 = *(const float4*)(vbase + (size_t)(jj + 3) * B * D);
        #pragma unroll
        for (int h = 0; h < H; ++h) {
            float4 wv = *(const float4*)(attn + ((size_t)b * H + h) * S + j0 + jj);
            acc[h].x += wv.x * v0.x + wv.y * v1.x + wv.z * v2.x + wv.w * v3.x;
            acc[h].y += wv.x * v0.y + wv.y * v1.y + wv.z * v2.y + wv.w * v3.y;
            acc[h].z += wv.x * v0.z + wv.y * v1.z + wv.z * v2.z + wv.w * v3.z;
            acc[h].w += wv.x * v0.w + wv.y * v1.w + wv.z * v2.w + wv.w * v3.w;
        }
    }
    float* ub = Upart + (((size_t)jt * B + b) * H) * D + tid * 4;
    #pragma unroll
    for (int h = 0; h < H; ++h) *(float4*)(ub + (size_t)h * D) = acc[h];
}

// --------------------- K5r: U[i] = sum_t U_part[t][i]  (f4 per thread)
__global__ __launch_bounds__(256) void k5r(const float* __restrict__ Upart,
                                           float* __restrict__ U, int JT) {
    int i = blockIdx.x * 256 + threadIdx.x;   // f4 index over B*H*D/4 = 65536
    float4 s = make_float4(0.f, 0.f, 0.f, 0.f);
    #pragma unroll 4
    for (int t = 0; t < JT; ++t) {
        float4 p = *(const float4*)(Upart + (size_t)t * (B * H * D) + (size_t)i * 4);
        s.x += p.x; s.y += p.y; s.z += p.z; s.w += p.w;
    }
    *(float4*)(U + (size_t)i * 4) = s;
}

// ------------- K6: x[b][h*128+d] += sum_e U[b][h][e] * Wv[e, h*128+d] (atomic)
__global__ __launch_bounds__(128) void k6_xv(const float* __restrict__ Wv,
                                             const float* __restrict__ U,
                                             float* __restrict__ x) {
    int d = threadIdx.x;
    int h = blockIdx.y;
    int e0 = blockIdx.x * 32;
    float acc[B] = {};
    #pragma unroll 4
    for (int ee = 0; ee < 32; ++ee) {
        int e = e0 + ee;
        float w = Wv[(size_t)e * D + h * DK + d];
        #pragma unroll
        for (int b = 0; b < B; ++b)
            acc[b] = fmaf(U[((size_t)b * H + h) * D + e], w, acc[b]);
    }
    #pragma unroll
    for (int b = 0; b < B; ++b) atomicAdd(&x[b * D + h * DK + d], acc[b]);
}

// ---------------------------------------- K7: out += x @ Wo (atomic, bo in K0)
__global__ __launch_bounds__(256) void k7_out(const float* __restrict__ x,
                                              const float* __restrict__ Wo,
                                              float* __restrict__ out) {
    int dout = blockIdx.x * 256 + threadIdx.x;
    int e0 = blockIdx.y * 64;
    float acc[B] = {};
    #pragma unroll 4
    for (int e = e0; e < e0 + 64; ++e) {
        float w = Wo[(size_t)e * D + dout];
        #pragma unroll
        for (int b = 0; b < B; ++b) acc[b] = fmaf(x[b * D + e], w, acc[b]);
    }
    #pragma unroll
    for (int b = 0; b < B; ++b) atomicAdd(&out[b * D + dout], acc[b]);
}

extern "C" void kernel_launch(void* const* d_in, const int* in_sizes, int n_in,
                              void* d_out, int out_size, void* d_ws, size_t ws_size,
                              hipStream_t stream) {
    const float* query   = (const float*)d_in[0];
    const float* key     = (const float*)d_in[1];
    const float* value   = (const float*)d_in[2];
    const float* Wq      = (const float*)d_in[3];
    const float* Wk      = (const float*)d_in[4];
    const float* Wv      = (const float*)d_in[5];
    const float* bv      = (const float*)d_in[6];
    const float* Wo      = (const float*)d_in[7];
    const float* bo      = (const float*)d_in[8];
    const float* key_pos = (const float*)d_in[9];
    const float* q_bias  = (const float*)d_in[10];
    float* out = (float*)d_out;

    float* ws     = (float*)d_ws;
    float* qq     = ws;                 // B*D        = 16384
    float* A      = ws + 16384;         // B*H*D      = 262144
    float* scores = ws + 278528;        // B*H*S      = 524288 (attn in place)
    float* U      = ws + 802816;        // B*H*D      = 262144
    float* x      = ws + 1064960;       // B*D        = 16384
    float* Upart  = ws + 1081344;       // JT * B*H*D

    // Pick largest JT (j-tiles in k5) whose partial buffer fits ws.
    int JT = 1;
    for (int cand = 64; cand >= 1; cand >>= 1) {
        size_t need = ((size_t)1081344 + (size_t)cand * 262144) * sizeof(float);
        if (need <= ws_size) { JT = cand; break; }
    }
    int jlen = S / JT;

    hipLaunchKernelGGL(k0_init,    dim3(64),        dim3(256), 0, stream, qq, x, out, q_bias, bv, bo);
    hipLaunchKernelGGL(k1_qproj,   dim3(8, 32),     dim3(256), 0, stream, query, Wq, qq);
    hipLaunchKernelGGL(k2_A,       dim3(512),       dim3(256), 0, stream, Wk, qq, A);
    hipLaunchKernelGGL(kq_pos,     dim3(512),       dim3(256), 0, stream, key_pos, qq, scores);
    hipLaunchKernelGGL(k3_scores,  dim3(64, 8),     dim3(256), 0, stream, key, A, scores);
    hipLaunchKernelGGL(k4_softmax, dim3(128),       dim3(256), 0, stream, scores);
    hipLaunchKernelGGL(k5_U,       dim3(JT, 8),     dim3(512), 0, stream, value, scores, Upart, jlen);
    hipLaunchKernelGGL(k5r,        dim3(256),       dim3(256), 0, stream, Upart, U, JT);
    hipLaunchKernelGGL(k6_xv,      dim3(64, 16),    dim3(128), 0, stream, Wv, U, x);
    hipLaunchKernelGGL(k7_out,     dim3(8, 32),     dim3(256), 0, stream, x, Wo, out);
}